// Round 1
// baseline (251.280 us; speedup 1.0000x reference)
//
#include <hip/hip_runtime.h>
#include <hip/hip_bf16.h>

// SequentialEdge: B=256 graphs, R=256 residues/graph, A=8 atoms/residue, D=2.
// Output layout (int32): 5 chunks (i = -2..2), chunk i has B*(R-|i|)*A*A rows
// of [node_in, node_out, i+D], rows = -1 where chain_id differs; then one
// trailing scalar (2D+1)=5.  Total ints = 62,619,649.
//
// Chunk table (edges):
//   i=-2: lo=2, Rv=254, Rv*64=16256, edge start = 0
//   i=-1: lo=1, Rv=255, Rv*64=16320, edge start = 4,161,536
//   i= 0: lo=0, Rv=256, Rv*64=16384, edge start = 8,339,456
//   i= 1: lo=0, Rv=255, Rv*64=16320, edge start = 12,533,760
//   i= 2: lo=0, Rv=254, Rv*64=16256, edge start = 16,711,680
//   total edges = 20,873,216 ; total ints = 62,619,648 (+1 scalar)
//
// Strategy: one thread per output int4 (perfect 16B/lane coalescing). Each
// int4 spans exactly 2 consecutive edges; decode both, rotate by j0%3.
// Divisors are compile-time constants per chunk branch -> magic multiplies.

#define E_TOTAL   20873216u
#define INT_TOTAL 62619648u
#define NT4       15654912u   // INT_TOTAL / 4

__device__ __forceinline__ void decode_edge(unsigned e, const int* __restrict__ ch,
                                            int& x, int& y, int& z) {
    unsigned g, rem;
    int i, lo, rel;
    if (e < 4161536u) {
        unsigned eo = e;
        g = eo / 16256u; rem = eo - g * 16256u; i = -2; lo = 2; rel = 0;
    } else if (e < 8339456u) {
        unsigned eo = e - 4161536u;
        g = eo / 16320u; rem = eo - g * 16320u; i = -1; lo = 1; rel = 1;
    } else if (e < 12533760u) {
        unsigned eo = e - 8339456u;
        g = eo >> 14;    rem = eo & 16383u;     i = 0;  lo = 0; rel = 2;
    } else if (e < 16711680u) {
        unsigned eo = e - 12533760u;
        g = eo / 16320u; rem = eo - g * 16320u; i = 1;  lo = 0; rel = 3;
    } else {
        unsigned eo = e - 16711680u;
        g = eo / 16256u; rem = eo - g * 16256u; i = 2;  lo = 0; rel = 4;
    }
    unsigned rl = (rem >> 6) + (unsigned)lo;   // local residue index
    unsigned ai = (rem >> 3) & 7u;             // in-atom (slow)
    unsigned ao = rem & 7u;                    // out-atom (fast)
    int res_in  = (int)(g * 256u + rl);
    int res_out = res_in + i;
    bool same = (ch[res_in] == ch[res_out]);
    x = same ? res_in  * 8 + (int)ai : -1;
    y = same ? res_out * 8 + (int)ao : -1;
    z = same ? rel : -1;
}

__global__ __launch_bounds__(256)
void seqedge_kernel(const int* __restrict__ chain, int* __restrict__ out) {
    unsigned t = blockIdx.x * 256u + threadIdx.x;
    if (t >= NT4) return;
    unsigned j0 = t * 4u;           // first int index this thread writes
    unsigned e0 = j0 / 3u;          // first edge touched
    unsigned c0 = j0 - e0 * 3u;     // component offset within edge e0
    unsigned e1 = e0 + 1u;
    if (e1 >= E_TOTAL) e1 = E_TOTAL - 1u;   // clamp (unused lanes of last int4)

    int x0, y0, z0, x1, y1, z1;
    decode_edge(e0, chain, x0, y0, z0);
    decode_edge(e1, chain, x1, y1, z1);

    int4 v;
    if (c0 == 0u)      v = make_int4(x0, y0, z0, x1);
    else if (c0 == 1u) v = make_int4(y0, z0, x1, y1);
    else               v = make_int4(z0, x1, y1, z1);

    reinterpret_cast<int4*>(out)[t] = v;

    if (t == 0u) out[INT_TOTAL] = 5;   // trailing scalar: num_relation = 2D+1
}

extern "C" void kernel_launch(void* const* d_in, const int* in_sizes, int n_in,
                              void* d_out, int out_size, void* d_ws, size_t ws_size,
                              hipStream_t stream) {
    const int* chain_id = (const int*)d_in[0];
    int* out = (int*)d_out;
    const unsigned nthreads = NT4;
    const unsigned nblocks = (nthreads + 255u) / 256u;   // 61152
    seqedge_kernel<<<nblocks, 256, 0, stream>>>(chain_id, out);
}